// Round 12
// baseline (965.596 us; speedup 1.0000x reference)
//
#include <hip/hip_runtime.h>
#include <hip/hip_bf16.h>
#include <math.h>

// ---------------------------------------------------------------------------
// GraphSAGE 2-layer forward.
// mean_j(x_j) @ W_r == mean_j(x_j @ W_r) -> project first, aggregate small.
// R12: keep R11's bf16 gather buffers (FETCH halved 194->98MB, model right)
// but fix the occupancy collapse it caused: fused2 VGPR 36->124 (compiler
// load-batching around bf16 converts) dropped occupancy 60->19% and doubled
// duration. __launch_bounds__(256,6) caps VGPR at ~84 (R10 proof: kernel fits
// in 36) -> restores ~6 waves/SIMD of latency hiding. Same cap on agg2.
// ---------------------------------------------------------------------------

typedef __attribute__((ext_vector_type(8))) short bf16x8;
typedef __attribute__((ext_vector_type(4))) float f32x4;

static __device__ __forceinline__ unsigned short f2bf(float f) {
    unsigned int u = __builtin_bit_cast(unsigned int, f);
    unsigned int r = (u + 0x7FFFu + ((u >> 16) & 1u)) >> 16;   // RNE
    return (unsigned short)r;
}
static __device__ __forceinline__ float bf2f(unsigned short u) {
    unsigned int v = ((unsigned int)u) << 16;
    return __builtin_bit_cast(float, v);
}

// ---------------- CSR build ----------------

__global__ void k_count(const int* __restrict__ dst, int* __restrict__ cnt, int E) {
    int e = blockIdx.x * blockDim.x + threadIdx.x;
    if (e < E) atomicAdd(&cnt[dst[e]], 1);
}

__global__ void k_blocksum(const int* __restrict__ cnt, int* __restrict__ bsum, int N) {
    __shared__ int sm[256];
    int i = blockIdx.x * 256 + threadIdx.x;
    sm[threadIdx.x] = (i < N) ? cnt[i] : 0;
    __syncthreads();
    for (int s = 128; s > 0; s >>= 1) {
        if (threadIdx.x < s) sm[threadIdx.x] += sm[threadIdx.x + s];
        __syncthreads();
    }
    if (threadIdx.x == 0) bsum[blockIdx.x] = sm[0];
}

__global__ void k_scanbsum(int* __restrict__ bsum, int nb) {
    __shared__ int a[512], b[512];
    int t = threadIdx.x;
    int v = (t < nb) ? bsum[t] : 0;
    a[t] = v;
    __syncthreads();
    int* pin = a; int* pout = b;
    for (int o = 1; o < 512; o <<= 1) {
        pout[t] = (t >= o) ? pin[t] + pin[t - o] : pin[t];
        __syncthreads();
        int* tmp = pin; pin = pout; pout = tmp;
    }
    if (t < nb) bsum[t] = pin[t] - v;   // exclusive
}

__global__ void k_scanfinal(const int* __restrict__ cnt, const int* __restrict__ bsum,
                            int* __restrict__ off, int* __restrict__ cursor, int N) {
    __shared__ int a[256], b[256];
    int t = threadIdx.x;
    int i = blockIdx.x * 256 + t;
    int v = (i < N) ? cnt[i] : 0;
    a[t] = v;
    __syncthreads();
    int* pin = a; int* pout = b;
    for (int o = 1; o < 256; o <<= 1) {
        pout[t] = (t >= o) ? pin[t] + pin[t - o] : pin[t];
        __syncthreads();
        int* tmp = pin; pin = pout; pout = tmp;
    }
    if (i < N) {
        int ex = bsum[blockIdx.x] + pin[t] - v;
        off[i] = ex;
        cursor[i] = ex;
    }
}

// scatter, dst-range partitioned (pass = blockIdx.y): csr window L2-resident
__global__ void k_scatterp(const int* __restrict__ src, const int* __restrict__ dst,
                           int* __restrict__ cursor, int* __restrict__ csr,
                           int E, int range) {
    int e = blockIdx.x * blockDim.x + threadIdx.x;
    if (e < E) {
        int d = dst[e];
        int lo = blockIdx.y * range;
        if (d >= lo && d < lo + range) {
            int pos = atomicAdd(&cursor[d], 1);
            csr[pos] = src[e];
        }
    }
}

// ------- GEMM1 (MFMA): [y1l|y1r] = bf16(x)[N,256] @ bf16([W1_l | W1_r]) -----

__global__ __launch_bounds__(256) void k_gemm1(const float* __restrict__ x,
                                               const float* __restrict__ Wl,
                                               const float* __restrict__ Wr,
                                               float* __restrict__ y1l,
                                               unsigned short* __restrict__ y1r, int N) {
    __shared__ unsigned short xs[64][40];     // bf16 [row][k]
    __shared__ unsigned short wsm[128][40];   // bf16 [col][k]
    int tid = threadIdx.x;
    int row0 = blockIdx.x * 64;
    int lane = tid & 63;
    int wid = tid >> 6;
    int wm = wid >> 1;
    int wn = wid & 1;

    int xr = tid >> 2;
    int xq = tid & 3;
    int wc = tid >> 1;
    int wo = tid & 1;
    const float* wsrc = (wc < 64) ? (Wl + wc) : (Wr + (wc - 64));

    f32x4 acc[2][4];
    #pragma unroll
    for (int m = 0; m < 2; ++m)
        #pragma unroll
        for (int n = 0; n < 4; ++n) acc[m][n] = (f32x4){0.f, 0.f, 0.f, 0.f};

    for (int kk = 0; kk < 256; kk += 32) {
        {
            int grow = row0 + xr;
            float4 v0 = make_float4(0.f, 0.f, 0.f, 0.f);
            float4 v1 = make_float4(0.f, 0.f, 0.f, 0.f);
            if (grow < N) {
                const float* p = x + (size_t)grow * 256 + kk + xq * 8;
                v0 = *(const float4*)(p);
                v1 = *(const float4*)(p + 4);
            }
            bf16x8 pk;
            pk[0] = (short)f2bf(v0.x); pk[1] = (short)f2bf(v0.y);
            pk[2] = (short)f2bf(v0.z); pk[3] = (short)f2bf(v0.w);
            pk[4] = (short)f2bf(v1.x); pk[5] = (short)f2bf(v1.y);
            pk[6] = (short)f2bf(v1.z); pk[7] = (short)f2bf(v1.w);
            *(bf16x8*)(&xs[xr][xq * 8]) = pk;
        }
        {
            bf16x8 w0, w1;
            #pragma unroll
            for (int j = 0; j < 8; ++j)
                w0[j] = (short)f2bf(wsrc[(size_t)(kk + wo * 16 + j) * 64]);
            #pragma unroll
            for (int j = 0; j < 8; ++j)
                w1[j] = (short)f2bf(wsrc[(size_t)(kk + wo * 16 + 8 + j) * 64]);
            *(bf16x8*)(&wsm[wc][wo * 16])     = w0;
            *(bf16x8*)(&wsm[wc][wo * 16 + 8]) = w1;
        }
        __syncthreads();

        int fr = lane & 15;
        int ko = (lane >> 4) * 8;
        bf16x8 a0 = *(const bf16x8*)(&xs[wm * 32 + fr][ko]);
        bf16x8 a1 = *(const bf16x8*)(&xs[wm * 32 + 16 + fr][ko]);
        bf16x8 b0 = *(const bf16x8*)(&wsm[wn * 64 + fr][ko]);
        bf16x8 b1 = *(const bf16x8*)(&wsm[wn * 64 + 16 + fr][ko]);
        bf16x8 b2 = *(const bf16x8*)(&wsm[wn * 64 + 32 + fr][ko]);
        bf16x8 b3 = *(const bf16x8*)(&wsm[wn * 64 + 48 + fr][ko]);

        acc[0][0] = __builtin_amdgcn_mfma_f32_16x16x32_bf16(a0, b0, acc[0][0], 0, 0, 0);
        acc[0][1] = __builtin_amdgcn_mfma_f32_16x16x32_bf16(a0, b1, acc[0][1], 0, 0, 0);
        acc[0][2] = __builtin_amdgcn_mfma_f32_16x16x32_bf16(a0, b2, acc[0][2], 0, 0, 0);
        acc[0][3] = __builtin_amdgcn_mfma_f32_16x16x32_bf16(a0, b3, acc[0][3], 0, 0, 0);
        acc[1][0] = __builtin_amdgcn_mfma_f32_16x16x32_bf16(a1, b0, acc[1][0], 0, 0, 0);
        acc[1][1] = __builtin_amdgcn_mfma_f32_16x16x32_bf16(a1, b1, acc[1][1], 0, 0, 0);
        acc[1][2] = __builtin_amdgcn_mfma_f32_16x16x32_bf16(a1, b2, acc[1][2], 0, 0, 0);
        acc[1][3] = __builtin_amdgcn_mfma_f32_16x16x32_bf16(a1, b3, acc[1][3], 0, 0, 0);
        __syncthreads();
    }

    // epilogue: C col = lane&15, row = (lane>>4)*4 + r
    // wn==0 -> self cols 0..63 (fp32 y1l); wn==1 -> neighbor cols (bf16 y1r)
    int cn = lane & 15;
    int r4 = (lane >> 4) * 4;
    #pragma unroll
    for (int m = 0; m < 2; ++m) {
        #pragma unroll
        for (int r = 0; r < 4; ++r) {
            int row = row0 + wm * 32 + m * 16 + r4 + r;
            if (row < N) {
                if (wn == 0) {
                    float* yp = y1l + (size_t)row * 64 + cn;
                    yp[0]  = acc[m][0][r];
                    yp[16] = acc[m][1][r];
                    yp[32] = acc[m][2][r];
                    yp[48] = acc[m][3][r];
                } else {
                    unsigned short* yq = y1r + (size_t)row * 64 + cn;
                    yq[0]  = f2bf(acc[m][0][r]);
                    yq[16] = f2bf(acc[m][1][r]);
                    yq[32] = f2bf(acc[m][2][r]);
                    yq[48] = f2bf(acc[m][3][r]);
                }
            }
        }
    }
}

// ---- Fused: h_i = relu(y1l_i + mean(y1r[nbr]) + b1);  y2_i = h_i @ W2 ------

__global__ __launch_bounds__(256, 6) void k_fused2(const float* __restrict__ y1l,
                                                   const unsigned short* __restrict__ y1r,
                                                   const int* __restrict__ csr,
                                                   const int* __restrict__ off,
                                                   const int* __restrict__ cnt,
                                                   const float* __restrict__ b1,
                                                   const float* __restrict__ W2l,
                                                   const float* __restrict__ W2r,
                                                   float* __restrict__ y2l,
                                                   unsigned short* __restrict__ y2r, int N) {
    __shared__ float wsm[64][80];    // [k][col], cols 0-39 = W2l, 40-79 = W2r
    __shared__ float hrow[4][64];    // per-wave h_i scratch
    int tid = threadIdx.x;
    #pragma unroll
    for (int it = 0; it < 5; ++it) {
        int idx = tid + it * 256;            // 0..1279
        int k = idx / 20;
        int cq = idx % 20;
        const float* s = (cq < 10) ? (W2l + (size_t)k * 40 + cq * 4)
                                   : (W2r + (size_t)k * 40 + (cq - 10) * 4);
        *(float4*)(&wsm[k][cq * 4]) = *(const float4*)s;
    }
    __syncthreads();

    int lane = tid & 63;
    int wv = tid >> 6;
    int wid = blockIdx.x * 4 + wv;
    int nw = gridDim.x * 4;
    float bl = b1[lane];
    int cl = (lane < 40) ? 2 * lane : 0;

    for (int i = wid; i < N; i += nw) {
        int deg = cnt[i];
        int start = off[i];
        float a0 = 0.f, a1 = 0.f, a2 = 0.f, a3 = 0.f;
        for (int base = 0; base < deg; base += 64) {
            int m = min(64, deg - base);
            int s = (lane < m) ? csr[start + base + lane] : 0;
            int j = 0;
            for (; j + 4 <= m; j += 4) {
                int s0 = __shfl(s, j), s1 = __shfl(s, j + 1);
                int s2 = __shfl(s, j + 2), s3 = __shfl(s, j + 3);
                a0 += bf2f(y1r[(size_t)s0 * 64 + lane]);
                a1 += bf2f(y1r[(size_t)s1 * 64 + lane]);
                a2 += bf2f(y1r[(size_t)s2 * 64 + lane]);
                a3 += bf2f(y1r[(size_t)s3 * 64 + lane]);
            }
            for (; j < m; ++j) {
                int sj = __shfl(s, j);
                a0 += bf2f(y1r[(size_t)sj * 64 + lane]);
            }
        }
        float mean = (a0 + a1 + a2 + a3) / (float)max(deg, 1);
        float hv = fmaxf(y1l[(size_t)i * 64 + lane] + mean + bl, 0.f);

        hrow[wv][lane] = hv;
        float p0 = 0.f, p1 = 0.f;
        #pragma unroll
        for (int k4 = 0; k4 < 64; k4 += 4) {
            float4 hk = *(const float4*)(&hrow[wv][k4]);
            float2 w0 = *(const float2*)(&wsm[k4 + 0][cl]);
            float2 w1 = *(const float2*)(&wsm[k4 + 1][cl]);
            float2 w2 = *(const float2*)(&wsm[k4 + 2][cl]);
            float2 w3 = *(const float2*)(&wsm[k4 + 3][cl]);
            p0 += hk.x * w0.x + hk.y * w1.x + hk.z * w2.x + hk.w * w3.x;
            p1 += hk.x * w0.y + hk.y * w1.y + hk.z * w2.y + hk.w * w3.y;
        }
        // cols 0..39 (lane<20) = self part -> fp32 y2l; cols 40..79 -> bf16 y2r
        if (lane < 20) {
            *(float2*)(y2l + (size_t)i * 40 + cl) = make_float2(p0, p1);
        } else if (lane < 40) {
            unsigned int pk = (unsigned int)f2bf(p0) | ((unsigned int)f2bf(p1) << 16);
            *(unsigned int*)(y2r + (size_t)i * 40 + (cl - 40)) = pk;
        }
    }
}

// ---------------- Agg2 + bias + softmax -------------------------------------

__global__ __launch_bounds__(256, 6) void k_agg2(const float* __restrict__ y2l,
                                                 const unsigned short* __restrict__ y2r,
                                                 const int* __restrict__ csr,
                                                 const int* __restrict__ off,
                                                 const int* __restrict__ cnt,
                                                 const float* __restrict__ b2,
                                                 float* __restrict__ out, int N) {
    int lane = threadIdx.x & 63;
    int wid = (blockIdx.x * blockDim.x + threadIdx.x) >> 6;
    int nw = (gridDim.x * blockDim.x) >> 6;
    for (int i = wid; i < N; i += nw) {
        int deg = cnt[i];
        int start = off[i];
        float a0 = 0.f, a1 = 0.f, a2 = 0.f, a3 = 0.f;
        bool act = (lane < 40);
        for (int base = 0; base < deg; base += 64) {
            int m = min(64, deg - base);
            int s = (lane < m) ? csr[start + base + lane] : 0;
            int j = 0;
            for (; j + 4 <= m; j += 4) {
                int s0 = __shfl(s, j), s1 = __shfl(s, j + 1);
                int s2 = __shfl(s, j + 2), s3 = __shfl(s, j + 3);
                if (act) {
                    a0 += bf2f(y2r[(size_t)s0 * 40 + lane]);
                    a1 += bf2f(y2r[(size_t)s1 * 40 + lane]);
                    a2 += bf2f(y2r[(size_t)s2 * 40 + lane]);
                    a3 += bf2f(y2r[(size_t)s3 * 40 + lane]);
                }
            }
            for (; j < m; ++j) {
                int sj = __shfl(s, j);
                if (act) a0 += bf2f(y2r[(size_t)sj * 40 + lane]);
            }
        }
        float logit = -INFINITY;
        if (act) {
            float mean = (a0 + a1 + a2 + a3) / (float)max(deg, 1);
            logit = y2l[(size_t)i * 40 + lane] + mean + b2[lane];
        }
        float mx = logit;
        #pragma unroll
        for (int o = 32; o > 0; o >>= 1) mx = fmaxf(mx, __shfl_xor(mx, o));
        float e = act ? expf(logit - mx) : 0.f;
        float se = e;
        #pragma unroll
        for (int o = 32; o > 0; o >>= 1) se += __shfl_xor(se, o);
        if (act) out[(size_t)i * 40 + lane] = e / se;
    }
}

// ---------------- launch ----------------------------------------------------

extern "C" void kernel_launch(void* const* d_in, const int* in_sizes, int n_in,
                              void* d_out, int out_size, void* d_ws, size_t ws_size,
                              hipStream_t stream) {
    const float* x   = (const float*)d_in[0];
    const int*   ei  = (const int*)d_in[1];
    const float* W1l = (const float*)d_in[2];
    const float* W1r = (const float*)d_in[3];
    const float* b1  = (const float*)d_in[4];
    const float* W2l = (const float*)d_in[5];
    const float* W2r = (const float*)d_in[6];
    const float* b2  = (const float*)d_in[7];
    float* out = (float*)d_out;

    int N = in_sizes[0] / 256;
    int E = in_sizes[1] / 2;
    const int* srcp = ei;
    const int* dstp = ei + E;

    char* w = (char*)d_ws;
    auto alloc = [&](size_t bytes) {
        char* p = w;
        w += (bytes + 255) & ~(size_t)255;
        return p;
    };
    int nb = (N + 255) / 256;
    int*            cnt    = (int*)alloc((size_t)N * 4);
    int*            off    = (int*)alloc((size_t)N * 4);
    int*            cursor = (int*)alloc((size_t)N * 4);
    int*            bsum   = (int*)alloc((size_t)nb * 4);
    int*            csr    = (int*)alloc((size_t)E * 4);
    float*          y1l    = (float*)alloc((size_t)N * 64 * 4);
    unsigned short* y1r    = (unsigned short*)alloc((size_t)N * 64 * 2);
    float*          y2l    = (float*)alloc((size_t)N * 40 * 4);
    unsigned short* y2r    = (unsigned short*)alloc((size_t)N * 40 * 2);

    hipMemsetAsync(cnt, 0, (size_t)N * 4, stream);
    k_count<<<(E + 255) / 256, 256, 0, stream>>>(dstp, cnt, E);
    k_blocksum<<<nb, 256, 0, stream>>>(cnt, bsum, N);
    k_scanbsum<<<1, 512, 0, stream>>>(bsum, nb);
    k_scanfinal<<<nb, 256, 0, stream>>>(cnt, bsum, off, cursor, N);

    const int P = 4;
    int range = (N + P - 1) / P;               // 25K nodes -> 1.6MB csr window
    dim3 sgrid((E + 255) / 256, P);
    k_scatterp<<<sgrid, 256, 0, stream>>>(srcp, dstp, cursor, csr, E, range);

    k_gemm1<<<(N + 63) / 64, 256, 0, stream>>>(x, W1l, W1r, y1l, y1r, N);
    k_fused2<<<1792, 256, 0, stream>>>(y1l, y1r, csr, off, cnt, b1, W2l, W2r, y2l, y2r, N);
    k_agg2<<<2048, 256, 0, stream>>>(y2l, y2r, csr, off, cnt, b2, out, N);
}

// Round 13
// 361.529 us; speedup vs baseline: 2.6709x; 2.6709x over previous
//
#include <hip/hip_runtime.h>
#include <hip/hip_bf16.h>
#include <math.h>

// ---------------------------------------------------------------------------
// GraphSAGE 2-layer forward.
// mean_j(x_j) @ W_r == mean_j(x_j @ W_r) -> project first, aggregate small.
// R13: full revert to the R10 configuration (best: 363us). The R11/R12 bf16-
// gather experiment halved FETCH as predicted (194->98MB) but lost to codegen
// both ways: uncapped -> 124 VGPR / 19% occ (196us); capped(256,6) -> scratch
// spills, 1.9GB FETCH (730us). fp32 gather buffers + 36-VGPR fused2 it is.
// ---------------------------------------------------------------------------

typedef __attribute__((ext_vector_type(8))) short bf16x8;
typedef __attribute__((ext_vector_type(4))) float f32x4;

static __device__ __forceinline__ unsigned short f2bf(float f) {
    unsigned int u = __builtin_bit_cast(unsigned int, f);
    unsigned int r = (u + 0x7FFFu + ((u >> 16) & 1u)) >> 16;   // RNE
    return (unsigned short)r;
}

// ---------------- CSR build ----------------

__global__ void k_count(const int* __restrict__ dst, int* __restrict__ cnt, int E) {
    int e = blockIdx.x * blockDim.x + threadIdx.x;
    if (e < E) atomicAdd(&cnt[dst[e]], 1);
}

__global__ void k_blocksum(const int* __restrict__ cnt, int* __restrict__ bsum, int N) {
    __shared__ int sm[256];
    int i = blockIdx.x * 256 + threadIdx.x;
    sm[threadIdx.x] = (i < N) ? cnt[i] : 0;
    __syncthreads();
    for (int s = 128; s > 0; s >>= 1) {
        if (threadIdx.x < s) sm[threadIdx.x] += sm[threadIdx.x + s];
        __syncthreads();
    }
    if (threadIdx.x == 0) bsum[blockIdx.x] = sm[0];
}

__global__ void k_scanbsum(int* __restrict__ bsum, int nb) {
    __shared__ int a[512], b[512];
    int t = threadIdx.x;
    int v = (t < nb) ? bsum[t] : 0;
    a[t] = v;
    __syncthreads();
    int* pin = a; int* pout = b;
    for (int o = 1; o < 512; o <<= 1) {
        pout[t] = (t >= o) ? pin[t] + pin[t - o] : pin[t];
        __syncthreads();
        int* tmp = pin; pin = pout; pout = tmp;
    }
    if (t < nb) bsum[t] = pin[t] - v;   // exclusive
}

__global__ void k_scanfinal(const int* __restrict__ cnt, const int* __restrict__ bsum,
                            int* __restrict__ off, int* __restrict__ cursor, int N) {
    __shared__ int a[256], b[256];
    int t = threadIdx.x;
    int i = blockIdx.x * 256 + t;
    int v = (i < N) ? cnt[i] : 0;
    a[t] = v;
    __syncthreads();
    int* pin = a; int* pout = b;
    for (int o = 1; o < 256; o <<= 1) {
        pout[t] = (t >= o) ? pin[t] + pin[t - o] : pin[t];
        __syncthreads();
        int* tmp = pin; pin = pout; pout = tmp;
    }
    if (i < N) {
        int ex = bsum[blockIdx.x] + pin[t] - v;
        off[i] = ex;
        cursor[i] = ex;
    }
}

// scatter, dst-range partitioned: pass = blockIdx.y commits only edges whose
// dst lies in [pass*range, pass*range+range) -> csr window L2-resident.
__global__ void k_scatterp(const int* __restrict__ src, const int* __restrict__ dst,
                           int* __restrict__ cursor, int* __restrict__ csr,
                           int E, int range) {
    int e = blockIdx.x * blockDim.x + threadIdx.x;
    if (e < E) {
        int d = dst[e];
        int lo = blockIdx.y * range;
        if (d >= lo && d < lo + range) {
            int pos = atomicAdd(&cursor[d], 1);
            csr[pos] = src[e];
        }
    }
}

// ------- GEMM1 (MFMA): y1[N,128] = bf16(x)[N,256] @ bf16([W1_l | W1_r]) -----

__global__ __launch_bounds__(256) void k_gemm1(const float* __restrict__ x,
                                               const float* __restrict__ Wl,
                                               const float* __restrict__ Wr,
                                               float* __restrict__ y1, int N) {
    __shared__ unsigned short xs[64][40];     // bf16 [row][k]
    __shared__ unsigned short wsm[128][40];   // bf16 [col][k]
    int tid = threadIdx.x;
    int row0 = blockIdx.x * 64;
    int lane = tid & 63;
    int wid = tid >> 6;
    int wm = wid >> 1;
    int wn = wid & 1;

    int xr = tid >> 2;
    int xq = tid & 3;
    int wc = tid >> 1;
    int wo = tid & 1;
    const float* wsrc = (wc < 64) ? (Wl + wc) : (Wr + (wc - 64));

    f32x4 acc[2][4];
    #pragma unroll
    for (int m = 0; m < 2; ++m)
        #pragma unroll
        for (int n = 0; n < 4; ++n) acc[m][n] = (f32x4){0.f, 0.f, 0.f, 0.f};

    for (int kk = 0; kk < 256; kk += 32) {
        {
            int grow = row0 + xr;
            float4 v0 = make_float4(0.f, 0.f, 0.f, 0.f);
            float4 v1 = make_float4(0.f, 0.f, 0.f, 0.f);
            if (grow < N) {
                const float* p = x + (size_t)grow * 256 + kk + xq * 8;
                v0 = *(const float4*)(p);
                v1 = *(const float4*)(p + 4);
            }
            bf16x8 pk;
            pk[0] = (short)f2bf(v0.x); pk[1] = (short)f2bf(v0.y);
            pk[2] = (short)f2bf(v0.z); pk[3] = (short)f2bf(v0.w);
            pk[4] = (short)f2bf(v1.x); pk[5] = (short)f2bf(v1.y);
            pk[6] = (short)f2bf(v1.z); pk[7] = (short)f2bf(v1.w);
            *(bf16x8*)(&xs[xr][xq * 8]) = pk;
        }
        {
            bf16x8 w0, w1;
            #pragma unroll
            for (int j = 0; j < 8; ++j)
                w0[j] = (short)f2bf(wsrc[(size_t)(kk + wo * 16 + j) * 64]);
            #pragma unroll
            for (int j = 0; j < 8; ++j)
                w1[j] = (short)f2bf(wsrc[(size_t)(kk + wo * 16 + 8 + j) * 64]);
            *(bf16x8*)(&wsm[wc][wo * 16])     = w0;
            *(bf16x8*)(&wsm[wc][wo * 16 + 8]) = w1;
        }
        __syncthreads();

        int fr = lane & 15;
        int ko = (lane >> 4) * 8;
        bf16x8 a0 = *(const bf16x8*)(&xs[wm * 32 + fr][ko]);
        bf16x8 a1 = *(const bf16x8*)(&xs[wm * 32 + 16 + fr][ko]);
        bf16x8 b0 = *(const bf16x8*)(&wsm[wn * 64 + fr][ko]);
        bf16x8 b1 = *(const bf16x8*)(&wsm[wn * 64 + 16 + fr][ko]);
        bf16x8 b2 = *(const bf16x8*)(&wsm[wn * 64 + 32 + fr][ko]);
        bf16x8 b3 = *(const bf16x8*)(&wsm[wn * 64 + 48 + fr][ko]);

        acc[0][0] = __builtin_amdgcn_mfma_f32_16x16x32_bf16(a0, b0, acc[0][0], 0, 0, 0);
        acc[0][1] = __builtin_amdgcn_mfma_f32_16x16x32_bf16(a0, b1, acc[0][1], 0, 0, 0);
        acc[0][2] = __builtin_amdgcn_mfma_f32_16x16x32_bf16(a0, b2, acc[0][2], 0, 0, 0);
        acc[0][3] = __builtin_amdgcn_mfma_f32_16x16x32_bf16(a0, b3, acc[0][3], 0, 0, 0);
        acc[1][0] = __builtin_amdgcn_mfma_f32_16x16x32_bf16(a1, b0, acc[1][0], 0, 0, 0);
        acc[1][1] = __builtin_amdgcn_mfma_f32_16x16x32_bf16(a1, b1, acc[1][1], 0, 0, 0);
        acc[1][2] = __builtin_amdgcn_mfma_f32_16x16x32_bf16(a1, b2, acc[1][2], 0, 0, 0);
        acc[1][3] = __builtin_amdgcn_mfma_f32_16x16x32_bf16(a1, b3, acc[1][3], 0, 0, 0);
        __syncthreads();
    }

    int cn = lane & 15;
    int r4 = (lane >> 4) * 4;
    #pragma unroll
    for (int m = 0; m < 2; ++m) {
        #pragma unroll
        for (int r = 0; r < 4; ++r) {
            int row = row0 + wm * 32 + m * 16 + r4 + r;
            if (row < N) {
                float* yp = y1 + (size_t)row * 128 + wn * 64 + cn;
                yp[0]  = acc[m][0][r];
                yp[16] = acc[m][1][r];
                yp[32] = acc[m][2][r];
                yp[48] = acc[m][3][r];
            }
        }
    }
}

// ---- Fused: h_i = relu(xl_i + mean(xr[nbr]) + b1);  y2_i = h_i @ [W2l|W2r] ----

__global__ __launch_bounds__(256) void k_fused2(const float* __restrict__ y1,
                                                const int* __restrict__ csr,
                                                const int* __restrict__ off,
                                                const int* __restrict__ cnt,
                                                const float* __restrict__ b1,
                                                const float* __restrict__ W2l,
                                                const float* __restrict__ W2r,
                                                float* __restrict__ y2, int N) {
    __shared__ float wsm[64][80];    // [k][col], cols 0-39 = W2l, 40-79 = W2r
    __shared__ float hrow[4][64];    // per-wave h_i scratch
    int tid = threadIdx.x;
    #pragma unroll
    for (int it = 0; it < 5; ++it) {
        int idx = tid + it * 256;            // 0..1279
        int k = idx / 20;
        int cq = idx % 20;
        const float* s = (cq < 10) ? (W2l + (size_t)k * 40 + cq * 4)
                                   : (W2r + (size_t)k * 40 + (cq - 10) * 4);
        *(float4*)(&wsm[k][cq * 4]) = *(const float4*)s;
    }
    __syncthreads();

    int lane = tid & 63;
    int wv = tid >> 6;
    int wid = blockIdx.x * 4 + wv;
    int nw = gridDim.x * 4;
    float bl = b1[lane];
    int cl = (lane < 40) ? 2 * lane : 0;

    for (int i = wid; i < N; i += nw) {
        int deg = cnt[i];
        int start = off[i];
        float a0 = 0.f, a1 = 0.f, a2 = 0.f, a3 = 0.f;
        for (int base = 0; base < deg; base += 64) {
            int m = min(64, deg - base);
            int s = (lane < m) ? csr[start + base + lane] : 0;
            int j = 0;
            for (; j + 4 <= m; j += 4) {
                int s0 = __shfl(s, j), s1 = __shfl(s, j + 1);
                int s2 = __shfl(s, j + 2), s3 = __shfl(s, j + 3);
                a0 += y1[(size_t)s0 * 128 + 64 + lane];
                a1 += y1[(size_t)s1 * 128 + 64 + lane];
                a2 += y1[(size_t)s2 * 128 + 64 + lane];
                a3 += y1[(size_t)s3 * 128 + 64 + lane];
            }
            for (; j < m; ++j) {
                int sj = __shfl(s, j);
                a0 += y1[(size_t)sj * 128 + 64 + lane];
            }
        }
        float mean = (a0 + a1 + a2 + a3) / (float)max(deg, 1);
        float hv = fmaxf(y1[(size_t)i * 128 + lane] + mean + bl, 0.f);

        hrow[wv][lane] = hv;
        float p0 = 0.f, p1 = 0.f;
        #pragma unroll
        for (int k4 = 0; k4 < 64; k4 += 4) {
            float4 hk = *(const float4*)(&hrow[wv][k4]);
            float2 w0 = *(const float2*)(&wsm[k4 + 0][cl]);
            float2 w1 = *(const float2*)(&wsm[k4 + 1][cl]);
            float2 w2 = *(const float2*)(&wsm[k4 + 2][cl]);
            float2 w3 = *(const float2*)(&wsm[k4 + 3][cl]);
            p0 += hk.x * w0.x + hk.y * w1.x + hk.z * w2.x + hk.w * w3.x;
            p1 += hk.x * w0.y + hk.y * w1.y + hk.z * w2.y + hk.w * w3.y;
        }
        if (lane < 40)
            *(float2*)(y2 + (size_t)i * 80 + cl) = make_float2(p0, p1);
    }
}

// ---------------- Agg2 + bias + softmax -------------------------------------

__global__ void k_agg2(const float* __restrict__ y2, const int* __restrict__ csr,
                       const int* __restrict__ off, const int* __restrict__ cnt,
                       const float* __restrict__ b2, float* __restrict__ out, int N) {
    int lane = threadIdx.x & 63;
    int wid = (blockIdx.x * blockDim.x + threadIdx.x) >> 6;
    int nw = (gridDim.x * blockDim.x) >> 6;
    for (int i = wid; i < N; i += nw) {
        int deg = cnt[i];
        int start = off[i];
        float a0 = 0.f, a1 = 0.f, a2 = 0.f, a3 = 0.f;
        bool act = (lane < 40);
        for (int base = 0; base < deg; base += 64) {
            int m = min(64, deg - base);
            int s = (lane < m) ? csr[start + base + lane] : 0;
            int j = 0;
            for (; j + 4 <= m; j += 4) {
                int s0 = __shfl(s, j), s1 = __shfl(s, j + 1);
                int s2 = __shfl(s, j + 2), s3 = __shfl(s, j + 3);
                if (act) {
                    a0 += y2[(size_t)s0 * 80 + 40 + lane];
                    a1 += y2[(size_t)s1 * 80 + 40 + lane];
                    a2 += y2[(size_t)s2 * 80 + 40 + lane];
                    a3 += y2[(size_t)s3 * 80 + 40 + lane];
                }
            }
            for (; j < m; ++j) {
                int sj = __shfl(s, j);
                if (act) a0 += y2[(size_t)sj * 80 + 40 + lane];
            }
        }
        float logit = -INFINITY;
        if (act) {
            float mean = (a0 + a1 + a2 + a3) / (float)max(deg, 1);
            logit = y2[(size_t)i * 80 + lane] + mean + b2[lane];
        }
        float mx = logit;
        #pragma unroll
        for (int o = 32; o > 0; o >>= 1) mx = fmaxf(mx, __shfl_xor(mx, o));
        float e = act ? expf(logit - mx) : 0.f;
        float se = e;
        #pragma unroll
        for (int o = 32; o > 0; o >>= 1) se += __shfl_xor(se, o);
        if (act) out[(size_t)i * 40 + lane] = e / se;
    }
}

// ---------------- launch ----------------------------------------------------

extern "C" void kernel_launch(void* const* d_in, const int* in_sizes, int n_in,
                              void* d_out, int out_size, void* d_ws, size_t ws_size,
                              hipStream_t stream) {
    const float* x   = (const float*)d_in[0];
    const int*   ei  = (const int*)d_in[1];
    const float* W1l = (const float*)d_in[2];
    const float* W1r = (const float*)d_in[3];
    const float* b1  = (const float*)d_in[4];
    const float* W2l = (const float*)d_in[5];
    const float* W2r = (const float*)d_in[6];
    const float* b2  = (const float*)d_in[7];
    float* out = (float*)d_out;

    int N = in_sizes[0] / 256;
    int E = in_sizes[1] / 2;
    const int* srcp = ei;
    const int* dstp = ei + E;

    char* w = (char*)d_ws;
    auto alloc = [&](size_t bytes) {
        char* p = w;
        w += (bytes + 255) & ~(size_t)255;
        return p;
    };
    int nb = (N + 255) / 256;
    int*   cnt    = (int*)alloc((size_t)N * 4);
    int*   off    = (int*)alloc((size_t)N * 4);
    int*   cursor = (int*)alloc((size_t)N * 4);
    int*   bsum   = (int*)alloc((size_t)nb * 4);
    int*   csr    = (int*)alloc((size_t)E * 4);
    float* y1     = (float*)alloc((size_t)N * 128 * 4);
    float* y2     = (float*)alloc((size_t)N * 80 * 4);

    hipMemsetAsync(cnt, 0, (size_t)N * 4, stream);
    k_count<<<(E + 255) / 256, 256, 0, stream>>>(dstp, cnt, E);
    k_blocksum<<<nb, 256, 0, stream>>>(cnt, bsum, N);
    k_scanbsum<<<1, 512, 0, stream>>>(bsum, nb);
    k_scanfinal<<<nb, 256, 0, stream>>>(cnt, bsum, off, cursor, N);

    const int P = 4;
    int range = (N + P - 1) / P;               // 25K nodes -> 1.6MB csr window
    dim3 sgrid((E + 255) / 256, P);
    k_scatterp<<<sgrid, 256, 0, stream>>>(srcp, dstp, cursor, csr, E, range);

    k_gemm1<<<(N + 63) / 64, 256, 0, stream>>>(x, W1l, W1r, y1, N);
    k_fused2<<<1792, 256, 0, stream>>>(y1, csr, off, cnt, b1, W2l, W2r, y2, N);
    k_agg2<<<2048, 256, 0, stream>>>(y2, csr, off, cnt, b2, out, N);
}